// Round 8
// baseline (1473.205 us; speedup 1.0000x reference)
//
#include <hip/hip_runtime.h>
#include <hip/hip_bf16.h>
#include <stdint.h>

// ---------------------------------------------------------------------------
// B=256 D=28 N=23 F=128 O=64 H=128 Y=7.  NBSEQ=5888.
// R8: kernB -> 92 blocks x 64 seqs (nt=4).  Mechanism: per-CU weight stream
//     (491KB/step from L2, ~9K cyc/step) was the floor; 64 seqs/block halves
//     per-seq weight cost.  x is hi-only bf16 (LDS budget; h stays hi+lo).
//     c-states in registers (AGPR-class next to acc), biases/x2 in LDS.
//     kernA / kernPrep unchanged from R7.
// ---------------------------------------------------------------------------

#define DB 256
#define DD 28
#define DN 23
#define DF 128
#define DO 64
#define DH 128
#define DY 7
#define NBSEQ (DN*DB)
#define ADJSZ (DB*DD*DN*DN)
#define GBLKB 92

#define WB0_OFF   47480832u
#define WB1_OFF   47710208u
#define GWT_OFFB  47972352u

using v8bf  = __attribute__((ext_vector_type(8))) __bf16;
using f32x4 = __attribute__((ext_vector_type(4))) float;
using u32x4 = __attribute__((ext_vector_type(4))) unsigned int;

__device__ __forceinline__ float fsig(float x)  { return 1.f/(1.f+__expf(-x)); }
__device__ __forceinline__ float ftanh(float x) { return 1.f - 2.f/(__expf(2.f*x)+1.f); }

__device__ __forceinline__ unsigned short f2bf(float f){
    unsigned u = __builtin_bit_cast(unsigned, f);
    return (unsigned short)((u + 0x7FFFu + ((u>>16)&1u)) >> 16);
}
__device__ __forceinline__ float bf2f(unsigned short b){
    return __builtin_bit_cast(float, (unsigned)b << 16);
}
__device__ __forceinline__ uint4 ntload4(const uint4* p){
    u32x4 v = __builtin_nontemporal_load((const u32x4*)p);
    return *(uint4*)&v;
}

#define FMA4(xv, wv, a) fmaf((xv).w,(wv).w, fmaf((xv).z,(wv).z, fmaf((xv).y,(wv).y, fmaf((xv).x,(wv).x,(a)))))
#define MFMA_(acc_, A_, B_) acc_ = __builtin_amdgcn_mfma_f32_16x16x32_bf16(A_, B_, acc_, 0, 0, 0)

// ---------------------------------------------------------------------------
// Prep (unchanged R7): j-remapped A-frag weights; gwt transpose.
// ---------------------------------------------------------------------------
__global__ __launch_bounds__(256) void kernPrep(
    const float* __restrict__ wih0, const float* __restrict__ whh0,
    const float* __restrict__ wih1, const float* __restrict__ whh1,
    const float* __restrict__ gcn_w,
    unsigned short* __restrict__ wb0, unsigned short* __restrict__ wb1,
    float* __restrict__ gwt)
{
    int idx = blockIdx.x*256 + threadIdx.x;
    if (idx < 114688){
        int e = idx&7, l = (idx>>3)&63, mt = (idx>>9)&31, kt = idx>>14;
        int rit = l&15, lj = rit>>2, g = rit&3;
        int r = g*128 + (mt>>2)*16 + lj*4 + (mt&3);
        int k = kt*32 + (l>>4)*8 + e;
        float v = 0.f;
        if (k < 65)                  v = wih0[r*65 + k];
        else if (k >= 72 && k < 200) v = whh0[r*128 + (k-72)];
        wb0[idx] = f2bf(v);
        return;
    }
    idx -= 114688;
    if (idx < 131072){
        int e = idx&7, l = (idx>>3)&63, mt = (idx>>9)&31, kt = idx>>14;
        int rit = l&15, lj = rit>>2, g = rit&3;
        int r = g*128 + (mt>>2)*16 + lj*4 + (mt&3);
        int k = kt*32 + (l>>4)*8 + e;
        float v = (k < 128) ? wih1[r*128 + k] : whh1[r*128 + (k-128)];
        wb1[idx] = f2bf(v);
        return;
    }
    idx -= 131072;
    if (idx < 8192){
        int o = idx >> 7, f = idx & 127;
        gwt[idx] = gcn_w[f*DO + o];
    }
}

// ---------------------------------------------------------------------------
// Kernel A (unchanged R7): per-(b,d) graph stage -> adj + zlin[bd][414].
// ---------------------------------------------------------------------------
__global__ __launch_bounds__(256) void kernA(
    const float* __restrict__ x, const float* __restrict__ adj_real,
    const float* __restrict__ infection, const int* __restrict__ day_order,
    const float* __restrict__ w1, const float* __restrict__ b1,
    const float* __restrict__ w2, const float* __restrict__ b2,
    const float* __restrict__ glp, const float* __restrict__ vvec,
    const float* __restrict__ gwt,
    float* __restrict__ out_adj, uint4* __restrict__ zlin4)
{
    const int bd = blockIdx.x;
    const int b  = bd / DD;
    const int t  = threadIdx.x;

    __shared__ float sm[11776];
    const int XS=0, N1=3036, N2=6072, S12=9108, ADJ=9660, XW=10212,
              DEG=11684, DINV=11707, FACT=11730, INFS=11753;
    const int XWP = N1;
    const int GC  = N1;

    const float* xg = x + (size_t)bd * (DN*DF);
    for (int p = t; p < DN*DF; p += 256) {
        int n = p >> 7, f = p & 127;
        sm[XS + n*132 + f] = xg[p];
    }
    if (t < DN) {
        float vv = vvec[t];
        sm[FACT + t] = __expf(vv*vv*(float)day_order[b]);
        sm[INFS + t] = infection[(size_t)bd*DN + t];
    }
    __syncthreads();

    {
        const int mat = t >> 7, fo = t & 127;
        const float* wr = (mat ? w2 : w1) + fo*DF;
        const float bias = (mat ? b2 : b1)[fo];
        float acc[DN];
        #pragma unroll
        for (int n=0;n<DN;n++) acc[n]=0.f;
        float4 w4 = *(const float4*)wr;
        for (int k4=0;k4<32;k4++){
            float4 wn = w4;
            if (k4 < 31) wn = *(const float4*)(wr + 4*(k4+1));
            #pragma unroll
            for (int n=0;n<DN;n++){
                float4 xv = *(const float4*)&sm[XS + n*132 + 4*k4];
                acc[n] = FMA4(xv, w4, acc[n]);
            }
            w4 = wn;
        }
        const int dst = mat ? N2 : N1;
        #pragma unroll
        for (int n=0;n<DN;n++) sm[dst + n*132 + fo] = ftanh(acc[n]+bias);
    }
    __syncthreads();

    if (t < DN) {
        const float* ar = adj_real + (size_t)bd*(DN*DN) + t*DN;
        float s = 0.f;
        for (int m=0;m<DN;m++) s += ar[m];
        sm[DEG+t] = s;
    }
    for (int p=t; p<DN*DN; p+=256){
        int i = p/DN, j = p - i*DN;
        float a = 0.f;
        for (int k4=0;k4<32;k4++){
            float4 av = *(const float4*)&sm[N1 + i*132 + 4*k4];
            float4 bv = *(const float4*)&sm[N2 + j*132 + 4*k4];
            a = FMA4(av, bv, a);
        }
        sm[S12 + i*24 + j] = a;
    }
    __syncthreads();

    for (int p=t; p<DN*DN; p+=256){
        int i=p/DN, j=p-i*DN;
        float al  = fmaxf(ftanh(sm[S12+i*24+j]-sm[S12+j*24+i]), 0.f);
        float md  = fsig(glp[i*DN+j]*sm[DEG+i]*sm[DEG+j]);
        float arv = adj_real[(size_t)bd*(DN*DN) + p];
        float adjv = al + md*arv;
        __builtin_nontemporal_store(adjv, &out_adj[(size_t)bd*(DN*DN) + p]);
        sm[ADJ + i*24 + j] = adjv + (i==j ? 1.f : 0.f);
    }
    __syncthreads();

    if (t<DN){
        float rs=0.f;
        for (int jj=0;jj<DN;jj++) rs += sm[ADJ+t*24+jj];
        sm[DINV+t] = rsqrtf(rs);
    }
    __syncthreads();
    for (int p=t;p<DN*DN;p+=256){
        int i=p/DN, j=p-i*DN;
        sm[ADJ+i*24+j] *= sm[DINV+i]*sm[DINV+j];
    }
    __syncthreads();

    {
        const int o = t & 63, q = t >> 6;
        float acc[DN];
        #pragma unroll
        for (int n=0;n<DN;n++) acc[n]=0.f;
        const float* gw = gwt + o*DF + q*32;
        for (int k4=0;k4<8;k4++){
            float4 w4 = *(const float4*)(gw + 4*k4);
            #pragma unroll
            for (int n=0;n<DN;n++){
                float4 xv = *(const float4*)&sm[XS + n*132 + q*32 + 4*k4];
                acc[n] = FMA4(xv, w4, acc[n]);
            }
        }
        #pragma unroll
        for (int n=0;n<DN;n++) sm[XWP + (q*DN+n)*64 + o] = acc[n];
    }
    __syncthreads();
    for (int p=t;p<DN*64;p+=256){
        int n=p>>6, o=p&63;
        sm[XW+p] = sm[XWP + n*64 + o] + sm[XWP + (DN+n)*64 + o]
                 + sm[XWP + (2*DN+n)*64 + o] + sm[XWP + (3*DN+n)*64 + o];
    }
    __syncthreads();

    for (int p=t;p<DN*64;p+=256){
        int n=p>>6, o=p&63;
        float a=0.f;
        #pragma unroll
        for (int m=0;m<DN;m++) a = fmaf(sm[ADJ+n*24+m], sm[XW+m*64+o], a);
        sm[GC + p] = fmaxf(a,0.f)*sm[FACT+n];
    }
    __syncthreads();

    for (int p=t; p<DN*18; p+=256){
        int n = p/18, r = p - n*18, hsel = r/9, k8 = r - hsel*9;
        __align__(16) unsigned short ob[8];
        #pragma unroll
        for (int e=0;e<8;e++){
            int k = k8*8+e;
            float v = (k<64) ? sm[GC + n*64 + k] : ((k==64) ? sm[INFS+n] : 0.f);
            unsigned short hb = f2bf(v);
            ob[e] = hsel ? f2bf(v - bf2f(hb)) : hb;
        }
        zlin4[(size_t)bd*414 + p] = *(const uint4*)ob;
    }
}

// ---------------------------------------------------------------------------
// Kernel B: MFMA LSTM.  grid=92, block=512 (8 waves), 64 seqs/block.
// Wave w: M-tiles 4w..4w+3 (j = 16w+lhi*4+mi), all 4 N-tiles (nt 0..3).
// x hi-only; h hi+lo.  c-states in registers.  3 barriers/step (enc).
// ---------------------------------------------------------------------------
#define XB0O  0            // 576 x 16 = 9216  (x hi, k8 0..8, 64 seq)
#define XB1O  9216
#define H0HI  18432        // 19 k8 (9..27) x 64 x 16 = 19456
#define H0LO  37888        // 20 k8 (8..27) x 64 x 16 = 20480 (slot0 = zeros)
#define U1HI  58368        // 32 k8 x 1024 = 32768
#define U1LO  91136        // 32768
#define X2O   123904       // [8][576] f32 = 18432
#define B0O   142336       // 512 f32
#define B1O   144384
#define FCO   146432       // 129 f32
#define INO   146952       // 64 f32
// end 147208

__global__ __launch_bounds__(512, 1) void kernB(
    const uint4* __restrict__ zlin, const v8bf* __restrict__ w0p, const v8bf* __restrict__ w1p,
    const float* __restrict__ b0g, const float* __restrict__ b1g,
    const float* __restrict__ infection, const float* __restrict__ fcw,
    const float* __restrict__ fcb, float* __restrict__ outy)
{
    const int t = threadIdx.x, blk = blockIdx.x;
    const int w = t>>6, l = t&63;
    const int lhi = l>>4, llo = l&15;
    __shared__ __align__(16) unsigned char smraw[147216];
    char* smb = (char*)smraw;

    // zero H0HI..B0O start (18432..142336)
    {
        uint4 z; z.x=z.y=z.z=z.w=0u;
        for (int i = t; i < (142336-18432)/16; i += 512) ((uint4*)(smb+18432))[i] = z;
    }
    ((float*)(smb+B0O))[t] = b0g[t];
    ((float*)(smb+B1O))[t] = b1g[t];
    if (t < 129) ((float*)(smb+FCO))[t] = (t<128) ? fcw[t] : fcb[0];
    if (t < 64){
        int gseq = blk*64 + t, n = gseq>>8, bb = gseq&255;
        float a = 0.f;
        for (int dd=0; dd<DD; dd++)
            a = fmaf(fcw[128+dd], infection[((size_t)bb*DD+dd)*DN+n], a);
        ((float*)(smb+INO))[t] = a;
    }

    // staging constants: unit u = k8*64 + sq (x hi only, 576 units)
    // thread t -> u1 = t ; u2 = 512+t (t<64)
    int k8u1 = t>>6,       sq1 = t&63;
    int k8u2 = 8,          sq2 = t;       // for t<64
    int gs1 = blk*64 + sq1, gs2 = blk*64 + sq2;
    size_t cb1 = (size_t)(gs1&255)*DD*414 + (gs1>>8)*18 + k8u1;
    size_t cb2 = (size_t)(gs2&255)*DD*414 + (gs2>>8)*18 + k8u2;
    int d1 = t*16, d2 = (512+t)*16;

    float c0[4][4], c1[4][4];
    #pragma unroll
    for (int mi=0;mi<4;mi++){
        #pragma unroll
        for (int nt=0;nt<4;nt++){ c0[mi][nt]=0.f; c1[mi][nt]=0.f; }
    }
    __syncthreads();

    // prologue: stage x(0) into XB0
    {
        uint4 a0 = ntload4(zlin + cb1);
        *(uint4*)(smb + XB0O + d1) = a0;
        if (t < 64){
            uint4 a1 = ntload4(zlin + cb2);
            *(uint4*)(smb + XB0O + d2) = a1;
        }
    }
    __syncthreads();

    const float* bias0L = (const float*)(smb+B0O);
    const float* bias1L = (const float*)(smb+B1O);

    for (int step = 0; step < DD + DY; ++step){
        const int xb  = (step & 1) ? XB1O : XB0O;
        const int xbn = (step & 1) ? XB0O : XB1O;
        const bool do_stage = (step + 1 < DD);

        // ---------------- L0 MFMA (+ stage x(step+1)) ----------------
        {
            uint4 sv0, sv1; sv0.x=sv0.y=sv0.z=sv0.w=0u; sv1 = sv0;
            if (do_stage){
                const uint4* sp = zlin + (size_t)(step+1)*414;
                sv0 = ntload4(sp + cb1);
                if (t < 64) sv1 = ntload4(sp + cb2);
            }
            f32x4 acc[4][4];
            #pragma unroll
            for (int mi=0;mi<4;mi++){
                int j = 16*w + lhi*4 + mi;
                f32x4 a;
                a[0]=bias0L[j]; a[1]=bias0L[128+j]; a[2]=bias0L[256+j]; a[3]=bias0L[384+j];
                #pragma unroll
                for (int nt=0;nt<4;nt++) acc[mi][nt] = a;
            }
            #pragma unroll
            for (int kt=0; kt<7; ++kt){
                const v8bf* wrow = w0p + (size_t)(kt*32 + w*4)*64 + l;
                v8bf A0 = wrow[0], A1 = wrow[64], A2 = wrow[128], A3 = wrow[192];
                int k8 = kt*4 + lhi;
                const char* hib = (k8 < 9) ? (smb + xb + k8*1024)
                                           : (smb + H0HI + (k8-9)*1024);
                v8bf BH[4];
                #pragma unroll
                for (int nt=0;nt<4;nt++) BH[nt] = *(const v8bf*)(hib + nt*256 + llo*16);
                #pragma unroll
                for (int nt=0;nt<4;nt++){
                    MFMA_(acc[0][nt], A0, BH[nt]);
                    MFMA_(acc[1][nt], A1, BH[nt]);
                    MFMA_(acc[2][nt], A2, BH[nt]);
                    MFMA_(acc[3][nt], A3, BH[nt]);
                }
                if (kt >= 2){
                    const char* lob = smb + H0LO + (k8-8)*1024;   // k8>=8 valid; slot0 zeros
                    v8bf BL[4];
                    #pragma unroll
                    for (int nt=0;nt<4;nt++) BL[nt] = *(const v8bf*)(lob + nt*256 + llo*16);
                    #pragma unroll
                    for (int nt=0;nt<4;nt++){
                        MFMA_(acc[0][nt], A0, BL[nt]);
                        MFMA_(acc[1][nt], A1, BL[nt]);
                        MFMA_(acc[2][nt], A2, BL[nt]);
                        MFMA_(acc[3][nt], A3, BL[nt]);
                    }
                }
            }
            if (do_stage){
                *(uint4*)(smb + xbn + d1) = sv0;
                if (t < 64) *(uint4*)(smb + xbn + d2) = sv1;
            }
            __syncthreads();   // B1: xb/H0 reads done

            // x2 accumulation of x(step) (xb intact; staging went to xbn)
            if (step < DD){
                float* xs = (float*)(smb + X2O);
                {
                    const unsigned short* hp = (const unsigned short*)(smb + xb + t*16);
                    #pragma unroll
                    for (int e=0;e<8;e++) xs[e*576+t] += bf2f(hp[e]);
                }
                if (t < 64){
                    const unsigned short* hp = (const unsigned short*)(smb + xb + (512+t)*16);
                    #pragma unroll
                    for (int e=0;e<8;e++) xs[e*576+512+t] += bf2f(hp[e]);
                }
            }

            // ACT L0 -> h0(step): H0 (for next L0) + U1 rows 0..15 (for L1)
            const int j8 = 2*w + (lhi>>1);
            const int sub = (lhi&1)*8;
            #pragma unroll
            for (int nt=0;nt<4;nt++){
                unsigned short hh[4], hl[4];
                #pragma unroll
                for (int mi=0;mi<4;mi++){
                    f32x4 a = acc[mi][nt];
                    float ii = fsig(a[0]), ff = fsig(a[1]), gg = ftanh(a[2]), oo = fsig(a[3]);
                    float c = ff*c0[mi][nt] + ii*gg;
                    c0[mi][nt] = c;
                    float h = oo*ftanh(c);
                    hh[mi] = f2bf(h);
                    hl[mi] = f2bf(h - bf2f(hh[mi]));
                }
                uint2 ph, pl;
                ph.x = (unsigned)hh[0] | ((unsigned)hh[1]<<16);
                ph.y = (unsigned)hh[2] | ((unsigned)hh[3]<<16);
                pl.x = (unsigned)hl[0] | ((unsigned)hl[1]<<16);
                pl.y = (unsigned)hl[2] | ((unsigned)hl[3]<<16);
                int so = (nt*16+llo)*16 + sub;
                *(uint2*)(smb + H0HI + j8*1024 + so)     = ph;   // k8 = 9+j8
                *(uint2*)(smb + H0LO + (j8+1)*1024 + so) = pl;   // slot k8-8
                *(uint2*)(smb + U1HI + j8*1024 + so)     = ph;
                *(uint2*)(smb + U1LO + j8*1024 + so)     = pl;
            }
            __syncthreads();   // B2: h0 visible
        }

        // ---------------- L1 MFMA ----------------
        {
            f32x4 acc1[4][4];
            #pragma unroll
            for (int mi=0;mi<4;mi++){
                int j = 16*w + lhi*4 + mi;
                f32x4 a;
                a[0]=bias1L[j]; a[1]=bias1L[128+j]; a[2]=bias1L[256+j]; a[3]=bias1L[384+j];
                #pragma unroll
                for (int nt=0;nt<4;nt++) acc1[mi][nt] = a;
            }
            #pragma unroll
            for (int kt=0; kt<8; ++kt){
                const v8bf* wrow = w1p + (size_t)(kt*32 + w*4)*64 + l;
                v8bf A0 = wrow[0], A1 = wrow[64], A2 = wrow[128], A3 = wrow[192];
                int k8 = kt*4 + lhi;
                const char* hib = smb + U1HI + k8*1024;
                const char* lob = smb + U1LO + k8*1024;
                v8bf BH[4], BL[4];
                #pragma unroll
                for (int nt=0;nt<4;nt++){
                    BH[nt] = *(const v8bf*)(hib + nt*256 + llo*16);
                    BL[nt] = *(const v8bf*)(lob + nt*256 + llo*16);
                }
                #pragma unroll
                for (int nt=0;nt<4;nt++){
                    MFMA_(acc1[0][nt], A0, BH[nt]);
                    MFMA_(acc1[1][nt], A1, BH[nt]);
                    MFMA_(acc1[2][nt], A2, BH[nt]);
                    MFMA_(acc1[3][nt], A3, BH[nt]);
                }
                #pragma unroll
                for (int nt=0;nt<4;nt++){
                    MFMA_(acc1[0][nt], A0, BL[nt]);
                    MFMA_(acc1[1][nt], A1, BL[nt]);
                    MFMA_(acc1[2][nt], A2, BL[nt]);
                    MFMA_(acc1[3][nt], A3, BL[nt]);
                }
            }
            __syncthreads();   // B3: U1 reads done

            // ACT L1 -> h1(step): U1 rows 16..31
            const int j8 = 2*w + (lhi>>1);
            const int sub = (lhi&1)*8;
            #pragma unroll
            for (int nt=0;nt<4;nt++){
                unsigned short hh[4], hl[4];
                #pragma unroll
                for (int mi=0;mi<4;mi++){
                    f32x4 a = acc1[mi][nt];
                    float ii = fsig(a[0]), ff = fsig(a[1]), gg = ftanh(a[2]), oo = fsig(a[3]);
                    float c = ff*c1[mi][nt] + ii*gg;
                    c1[mi][nt] = c;
                    float h = oo*ftanh(c);
                    hh[mi] = f2bf(h);
                    hl[mi] = f2bf(h - bf2f(hh[mi]));
                }
                uint2 ph, pl;
                ph.x = (unsigned)hh[0] | ((unsigned)hh[1]<<16);
                ph.y = (unsigned)hh[2] | ((unsigned)hh[3]<<16);
                pl.x = (unsigned)hl[0] | ((unsigned)hl[1]<<16);
                pl.y = (unsigned)hl[2] | ((unsigned)hl[3]<<16);
                int so = (nt*16+llo)*16 + sub;
                *(uint2*)(smb + U1HI + (16+j8)*1024 + so) = ph;
                *(uint2*)(smb + U1LO + (16+j8)*1024 + so) = pl;
            }
        }

        // step 27: build decoder mean input into BOTH XB buffers (x hi-only)
        if (step == DD-1){
            __syncthreads();
            const float* xs = (const float*)(smb + X2O);
            {
                __align__(16) unsigned short hb8[8];
                #pragma unroll
                for (int e=0;e<8;e++) hb8[e] = f2bf(xs[e*576+t] * (1.f/(float)DD));
                *(uint4*)(smb + XB0O + t*16) = *(const uint4*)hb8;
                *(uint4*)(smb + XB1O + t*16) = *(const uint4*)hb8;
            }
            if (t < 64){
                __align__(16) unsigned short hb8[8];
                #pragma unroll
                for (int e=0;e<8;e++) hb8[e] = f2bf(xs[e*576+512+t] * (1.f/(float)DD));
                *(uint4*)(smb + XB0O + (512+t)*16) = *(const uint4*)hb8;
                *(uint4*)(smb + XB1O + (512+t)*16) = *(const uint4*)hb8;
            }
        }

        // decoder FC
        if (step >= DD){
            __syncthreads();   // h1 visible
            {
                int seq = t>>3, l8 = t&7;
                const float* fw = (const float*)(smb+FCO);
                float a = 0.f;
                #pragma unroll
                for (int half=0; half<2; ++half){
                    int k8 = 16 + l8*2 + half;
                    const unsigned short* uh = (const unsigned short*)(smb + U1HI + k8*1024 + seq*16);
                    const unsigned short* ul = (const unsigned short*)(smb + U1LO + k8*1024 + seq*16);
                    #pragma unroll
                    for (int e=0;e<8;e++){
                        int j = l8*16 + half*8 + e;
                        a = fmaf(fw[j], bf2f(uh[e]) + bf2f(ul[e]), a);
                    }
                }
                a += __shfl_down(a, 4, 8);
                a += __shfl_down(a, 2, 8);
                a += __shfl_down(a, 1, 8);
                if (l8 == 0){
                    int gseq = blk*64 + seq, n = gseq>>8, bb = gseq&255;
                    float yv = fmaxf(a + ((const float*)(smb+INO))[seq] + fw[128], 0.f);
                    __builtin_nontemporal_store(yv, &outy[((size_t)bb*DY + (step-DD))*DN + n]);
                }
            }
        }
        // no closing barrier (R7 scheme): next L0 reads xb parity (stable) and
        // H0 (rewritten only after next B1); FC/mean read regions disjoint from
        // next step's pre-B1 writes.
    }
}

// ---------------------------------------------------------------------------
extern "C" void kernel_launch(void* const* d_in, const int* in_sizes, int n_in,
                              void* d_out, int out_size, void* d_ws, size_t ws_size,
                              hipStream_t stream)
{
    const float* x         = (const float*)d_in[0];
    const float* adj_real  = (const float*)d_in[1];
    const float* infection = (const float*)d_in[2];
    const int*   day_order = (const int*)  d_in[3];
    const float* gl_w1     = (const float*)d_in[4];
    const float* gl_b1     = (const float*)d_in[5];
    const float* gl_w2     = (const float*)d_in[6];
    const float* gl_b2     = (const float*)d_in[7];
    const float* glp       = (const float*)d_in[8];
    const float* gcn_w     = (const float*)d_in[9];
    const float* vvec      = (const float*)d_in[10];
    const float* wih0      = (const float*)d_in[11];
    const float* whh0      = (const float*)d_in[12];
    const float* b0        = (const float*)d_in[13];
    const float* wih1      = (const float*)d_in[14];
    const float* whh1      = (const float*)d_in[15];
    const float* b1        = (const float*)d_in[16];
    const float* fcw       = (const float*)d_in[17];
    const float* fcb       = (const float*)d_in[18];

    uint8_t* wsb = (uint8_t*)d_ws;
    uint4*          zlin = (uint4*)(wsb);
    unsigned short* wb0  = (unsigned short*)(wsb + WB0_OFF);
    unsigned short* wb1  = (unsigned short*)(wsb + WB1_OFF);
    float*          gwt  = (float*)(wsb + GWT_OFFB);
    float* out_adj = (float*)d_out;
    float* out_y   = out_adj + ADJSZ;

    kernPrep<<<dim3(992), dim3(256), 0, stream>>>(wih0, whh0, wih1, whh1, gcn_w,
                                                  wb0, wb1, gwt);
    kernA<<<dim3(DB*DD), dim3(256), 0, stream>>>(x, adj_real, infection, day_order,
                                                 gl_w1, gl_b1, gl_w2, gl_b2, glp,
                                                 vvec, gwt, out_adj, zlin);
    kernB<<<dim3(GBLKB), dim3(512), 0, stream>>>(zlin, (const v8bf*)wb0,
                                                 (const v8bf*)wb1, b0, b1, infection,
                                                 fcw, fcb, out_y);
}

// Round 9
// 643.967 us; speedup vs baseline: 2.2877x; 2.2877x over previous
//
#include <hip/hip_runtime.h>
#include <hip/hip_bf16.h>
#include <stdint.h>

// ---------------------------------------------------------------------------
// B=256 D=28 N=23 F=128 O=64 H=128 Y=7.  NBSEQ=5888 = 184 blocks x 32 seqs.
// R9:
//  kernB: exact R7 revert (R8's 64-seq tile spilled: acc+frag arrays > 128-VGPR
//         cap -> 364MB scratch WRITE, 2.2x slower).
//  kernA: A2 (x@W1^T, x@W2^T) and A7 (x@gcn_w) moved to MFMA.  x staged once
//         as bf16 hi+lo in LDS [32][140] (zero-padded rows); W1/W2 packed
//         hi+lo B-frags (3-term MFMA product, ~2^-17 accuracy for the tight
//         adj threshold); gcn_w single-bf16 B-frag (2-term).
// ---------------------------------------------------------------------------

#define DB 256
#define DD 28
#define DN 23
#define DF 128
#define DO 64
#define DH 128
#define DY 7
#define NBSEQ (DN*DB)
#define ADJSZ (DB*DD*DN*DN)
#define GBLK 184

// workspace byte offsets
#define WB0_OFF   47480832u            // zlin = 7168*414*16
#define WB1_OFF   47710208u
#define WPK_OFF   47972352u            // 65536 bf16 = 131072 B
#define GPK_OFF   48103424u            // 8192 bf16 = 16384 B

using v8bf  = __attribute__((ext_vector_type(8))) __bf16;
using f32x4 = __attribute__((ext_vector_type(4))) float;
using u32x4 = __attribute__((ext_vector_type(4))) unsigned int;

__device__ __forceinline__ float fsig(float x)  { return 1.f/(1.f+__expf(-x)); }
__device__ __forceinline__ float ftanh(float x) { return 1.f - 2.f/(__expf(2.f*x)+1.f); }

__device__ __forceinline__ unsigned short f2bf(float f){
    unsigned u = __builtin_bit_cast(unsigned, f);
    return (unsigned short)((u + 0x7FFFu + ((u>>16)&1u)) >> 16);
}
__device__ __forceinline__ float bf2f(unsigned short b){
    return __builtin_bit_cast(float, (unsigned)b << 16);
}
__device__ __forceinline__ uint4 ntload4(const uint4* p){
    u32x4 v = __builtin_nontemporal_load((const u32x4*)p);
    return *(uint4*)&v;
}

#define MFMA_(acc_, A_, B_) acc_ = __builtin_amdgcn_mfma_f32_16x16x32_bf16(A_, B_, acc_, 0, 0, 0)

// ---------------------------------------------------------------------------
// Prep: wb0/wb1 LSTM A-frags (j-remap, unchanged R7); wpk = W1/W2 hi+lo
// B-frags; gpk = gcn_w bf16 B-frags.
// wpk elem idx: ((((mat*8+nt)*4+kt)*2+hsel)*64+l)*8+e ; fo=nt*16+(l&15),
// k=kt*32+(l>>4)*8+e ; v = gl_w{1,2}[fo*128+k].
// gpk elem idx: ((nt*4+kt)*64+l)*8+e ; o=nt*16+(l&15) ; v = gcn_w[k*64+o].
// ---------------------------------------------------------------------------
__global__ __launch_bounds__(256) void kernPrep(
    const float* __restrict__ wih0, const float* __restrict__ whh0,
    const float* __restrict__ wih1, const float* __restrict__ whh1,
    const float* __restrict__ glw1, const float* __restrict__ glw2,
    const float* __restrict__ gcn_w,
    unsigned short* __restrict__ wb0, unsigned short* __restrict__ wb1,
    unsigned short* __restrict__ wpk, unsigned short* __restrict__ gpk)
{
    int idx = blockIdx.x*256 + threadIdx.x;
    if (idx < 114688){
        int e = idx&7, l = (idx>>3)&63, mt = (idx>>9)&31, kt = idx>>14;
        int rit = l&15, lj = rit>>2, g = rit&3;
        int r = g*128 + (mt>>2)*16 + lj*4 + (mt&3);
        int k = kt*32 + (l>>4)*8 + e;
        float v = 0.f;
        if (k < 65)                  v = wih0[r*65 + k];
        else if (k >= 72 && k < 200) v = whh0[r*128 + (k-72)];
        wb0[idx] = f2bf(v);
        return;
    }
    idx -= 114688;
    if (idx < 131072){
        int e = idx&7, l = (idx>>3)&63, mt = (idx>>9)&31, kt = idx>>14;
        int rit = l&15, lj = rit>>2, g = rit&3;
        int r = g*128 + (mt>>2)*16 + lj*4 + (mt&3);
        int k = kt*32 + (l>>4)*8 + e;
        float v = (k < 128) ? wih1[r*128 + k] : whh1[r*128 + (k-128)];
        wb1[idx] = f2bf(v);
        return;
    }
    idx -= 131072;
    if (idx < 65536){
        int e = idx&7, l = (idx>>3)&63, hsel = (idx>>9)&1, kt = (idx>>10)&3,
            nt = (idx>>12)&7, mat = (idx>>15)&1;
        int fo = nt*16 + (l&15);
        int k  = kt*32 + (l>>4)*8 + e;
        float v = (mat ? glw2 : glw1)[fo*128 + k];
        unsigned short hb = f2bf(v);
        wpk[idx] = hsel ? f2bf(v - bf2f(hb)) : hb;
        return;
    }
    idx -= 65536;
    if (idx < 8192){
        int e = idx&7, l = (idx>>3)&63, kt = (idx>>9)&3, nt = (idx>>11)&3;
        int o = nt*16 + (l&15);
        int k = kt*32 + (l>>4)*8 + e;
        gpk[idx] = f2bf(gcn_w[k*64 + o]);
    }
}

// ---------------------------------------------------------------------------
// Kernel A: per-(b,d) graph stage.  grid = 7168, block = 256 (4 waves).
// A2/A7 via MFMA.  LDS: sm[8740] f32 + xhl bf16 hi/lo [2][32][140].
// ---------------------------------------------------------------------------
__global__ __launch_bounds__(256) void kernA(
    const float* __restrict__ x, const float* __restrict__ adj_real,
    const float* __restrict__ infection, const int* __restrict__ day_order,
    const float* __restrict__ b1, const float* __restrict__ b2,
    const float* __restrict__ glp, const float* __restrict__ vvec,
    const v8bf* __restrict__ wpk, const v8bf* __restrict__ gpk,
    float* __restrict__ out_adj, uint4* __restrict__ zlin4)
{
    const int bd = blockIdx.x;
    const int b  = bd / DD;
    const int t  = threadIdx.x;
    const int w  = t>>6, l = t&63;

    __shared__ float sm[8740];
    const int N1=0, N2=3036, S12=6072, ADJ=6624, XW=7176, DEG=8648,
              DINV=8671, FACT=8694, INFS=8717;
    const int GC = N1;   // alias: N1 dead after A3
    __shared__ __align__(16) unsigned short xhl[2][32][140];

    // stage x -> bf16 hi/lo; zero pad rows 23..31
    const float* xg = x + (size_t)bd*(DN*DF);
    for (int p=t; p<DN*DF; p+=256){
        int n = p>>7, k = p&127;
        float v = xg[p];
        unsigned short hb = f2bf(v);
        xhl[0][n][k] = hb;
        xhl[1][n][k] = f2bf(v - bf2f(hb));
    }
    for (int p=t; p<9*DF; p+=256){
        int n = DN + (p>>7), k = p&127;
        xhl[0][n][k] = 0; xhl[1][n][k] = 0;
    }
    if (t < DN){
        float vv = vvec[t];
        sm[FACT+t] = __expf(vv*vv*(float)day_order[b]);
        sm[INFS+t] = infection[(size_t)bd*DN + t];
    }
    __syncthreads();

    // ---- A2 (MFMA): n1/n2 = tanh(x @ W^T + b).  wave w: mat=w>>1, nt base (w&1)*4.
    {
        const int mat = w>>1;
        const int ntb = (w&1)*4;
        const float* bsrc = mat ? b2 : b1;
        float bias[4];
        #pragma unroll
        for (int q=0;q<4;q++) bias[q] = bsrc[(ntb+q)*16 + (l&15)];
        f32x4 acc[2][4];
        #pragma unroll
        for (int mt=0;mt<2;mt++)
            #pragma unroll
            for (int q=0;q<4;q++){ f32x4 z; z[0]=z[1]=z[2]=z[3]=0.f; acc[mt][q]=z; }
        #pragma unroll
        for (int kt=0;kt<4;kt++){
            v8bf ah[2], al[2];
            #pragma unroll
            for (int mt=0;mt<2;mt++){
                int m = mt*16 + (l&15);
                int ko = (l>>4)*8 + kt*32;
                ah[mt] = *(const v8bf*)&xhl[0][m][ko];
                al[mt] = *(const v8bf*)&xhl[1][m][ko];
            }
            #pragma unroll
            for (int q=0;q<4;q++){
                const v8bf* wb = wpk + ((size_t)(((mat*8+(ntb+q))*4+kt)*2)*64 + l);
                v8bf wh = wb[0], wl = wb[64];
                MFMA_(acc[0][q], ah[0], wh);
                MFMA_(acc[1][q], ah[1], wh);
                MFMA_(acc[0][q], al[0], wh);
                MFMA_(acc[1][q], al[1], wh);
                MFMA_(acc[0][q], ah[0], wl);
                MFMA_(acc[1][q], ah[1], wl);
            }
        }
        const int dst = mat ? N2 : N1;
        #pragma unroll
        for (int mt=0;mt<2;mt++){
            #pragma unroll
            for (int q=0;q<4;q++){
                int fo = (ntb+q)*16 + (l&15);
                #pragma unroll
                for (int r=0;r<4;r++){
                    int n = mt*16 + (l>>4)*4 + r;
                    if (n < DN) sm[dst + n*132 + fo] = ftanh(acc[mt][q][r] + bias[q]);
                }
            }
        }
    }
    __syncthreads();

    // ---- A3: s12 + deg
    if (t < DN){
        const float* ar = adj_real + (size_t)bd*(DN*DN) + t*DN;
        float s = 0.f;
        for (int m=0;m<DN;m++) s += ar[m];
        sm[DEG+t] = s;
    }
    for (int p=t; p<DN*DN; p+=256){
        int i = p/DN, j = p - i*DN;
        float a = 0.f;
        for (int k4=0;k4<32;k4++){
            const float4 av = *(const float4*)&sm[N1 + i*132 + 4*k4];
            const float4 bv = *(const float4*)&sm[N2 + j*132 + 4*k4];
            a = fmaf(av.w,bv.w, fmaf(av.z,bv.z, fmaf(av.y,bv.y, fmaf(av.x,bv.x,a))));
        }
        sm[S12 + i*24 + j] = a;
    }
    __syncthreads();

    // ---- A4: adj
    for (int p=t; p<DN*DN; p+=256){
        int i=p/DN, j=p-i*DN;
        float al  = fmaxf(ftanh(sm[S12+i*24+j]-sm[S12+j*24+i]), 0.f);
        float md  = fsig(glp[i*DN+j]*sm[DEG+i]*sm[DEG+j]);
        float arv = adj_real[(size_t)bd*(DN*DN) + p];
        float adjv = al + md*arv;
        __builtin_nontemporal_store(adjv, &out_adj[(size_t)bd*(DN*DN) + p]);
        sm[ADJ + i*24 + j] = adjv + (i==j ? 1.f : 0.f);
    }
    __syncthreads();

    if (t<DN){
        float rs=0.f;
        for (int jj=0;jj<DN;jj++) rs += sm[ADJ+t*24+jj];
        sm[DINV+t] = rsqrtf(rs);
    }
    __syncthreads();

    // ---- A6 (dad in place) + A7 (MFMA xw = x @ gcn_w; wave w -> o-tile w)
    for (int p=t;p<DN*DN;p+=256){
        int i=p/DN, j=p-i*DN;
        sm[ADJ+i*24+j] *= sm[DINV+i]*sm[DINV+j];
    }
    {
        f32x4 acc2[2];
        { f32x4 z; z[0]=z[1]=z[2]=z[3]=0.f; acc2[0]=z; acc2[1]=z; }
        #pragma unroll
        for (int kt=0;kt<4;kt++){
            v8bf ah[2], al[2];
            #pragma unroll
            for (int mt=0;mt<2;mt++){
                int m = mt*16 + (l&15);
                int ko = (l>>4)*8 + kt*32;
                ah[mt] = *(const v8bf*)&xhl[0][m][ko];
                al[mt] = *(const v8bf*)&xhl[1][m][ko];
            }
            v8bf gh = gpk[(size_t)(w*4+kt)*64 + l];
            MFMA_(acc2[0], ah[0], gh);
            MFMA_(acc2[1], ah[1], gh);
            MFMA_(acc2[0], al[0], gh);
            MFMA_(acc2[1], al[1], gh);
        }
        int o = w*16 + (l&15);
        #pragma unroll
        for (int mt=0;mt<2;mt++){
            #pragma unroll
            for (int r=0;r<4;r++){
                int n = mt*16 + (l>>4)*4 + r;
                if (n < DN) sm[XW + n*64 + o] = acc2[mt][r];
            }
        }
    }
    __syncthreads();

    // ---- A8: gcn = relu(dad @ xw) * factor -> GC
    for (int p=t;p<DN*64;p+=256){
        int n=p>>6, o=p&63;
        float a=0.f;
        #pragma unroll
        for (int m=0;m<DN;m++) a = fmaf(sm[ADJ+n*24+m], sm[XW+m*64+o], a);
        sm[GC + p] = fmaxf(a,0.f)*sm[FACT+n];
    }
    __syncthreads();

    // ---- pack -> zlin[bd][414], p = n*18 + hsel*9 + k8 (coalesced)
    for (int p=t; p<DN*18; p+=256){
        int n = p/18, r = p - n*18, hsel = r/9, k8 = r - hsel*9;
        __align__(16) unsigned short ob[8];
        #pragma unroll
        for (int e=0;e<8;e++){
            int k = k8*8+e;
            float v = (k<64) ? sm[GC + n*64 + k] : ((k==64) ? sm[INFS+n] : 0.f);
            unsigned short hb = f2bf(v);
            ob[e] = hsel ? f2bf(v - bf2f(hb)) : hb;
        }
        zlin4[(size_t)bd*414 + p] = *(const uint4*)ob;
    }
}

// ---------------------------------------------------------------------------
// Kernel B: MFMA LSTM — exact R7 version (503us known-good).
// grid=184, block=512 (8 waves), 32 seqs/block.
// ---------------------------------------------------------------------------
#define XB0O 0
#define XB1O 9216
#define H0O  18432
#define U1O  37888
#define C0O  70656
#define C1O  87040
#define X2O  103424
#define B0O  112640
#define B1O  114688
#define FCO  116736
#define INO  117264

__global__ __launch_bounds__(512, 1) void kernB(
    const uint4* __restrict__ zlin, const v8bf* __restrict__ w0p, const v8bf* __restrict__ w1p,
    const float* __restrict__ b0g, const float* __restrict__ b1g,
    const float* __restrict__ infection, const float* __restrict__ fcw,
    const float* __restrict__ fcb, float* __restrict__ outy)
{
    const int t = threadIdx.x, blk = blockIdx.x;
    const int w = t>>6, l = t&63;
    const int lhi = l>>4, llo = l&15;
    __shared__ __align__(16) unsigned char smraw[117392];
    char* smb = (char*)smraw;

    {
        uint4 z; z.x=z.y=z.z=z.w=0u;
        for (int i = t; i < (112640-18432)/16; i += 512) ((uint4*)(smb+18432))[i] = z;
    }
    ((float*)(smb+B0O))[t] = b0g[t];
    ((float*)(smb+B1O))[t] = b1g[t];
    if (t < 129) ((float*)(smb+FCO))[t] = (t<128) ? fcw[t] : fcb[0];
    if (t < 32){
        int gseq = blk*32 + t, n = gseq>>8, bb = gseq&255;
        float a = 0.f;
        for (int dd=0; dd<DD; dd++)
            a = fmaf(fcw[128+dd], infection[((size_t)bb*DD+dd)*DN+n], a);
        ((float*)(smb+INO))[t] = a;
    }

    int u1 = w*72 + l;
    int u2 = u1 + 64;
    int hs1 = (u1 >= 288) ? 1 : 0;  int rm1 = u1 - hs1*288;
    int hs2 = (u2 >= 288) ? 1 : 0;  int rm2 = u2 - hs2*288;
    int k81 = rm1 >> 5, sq1 = rm1 & 31;
    int k82 = rm2 >> 5, sq2 = rm2 & 31;
    int gs1 = blk*32 + sq1, gs2 = blk*32 + sq2;
    size_t cb1 = (size_t)(gs1 & 255)*DD*414 + (gs1>>8)*18 + hs1*9 + k81;
    size_t cb2 = (size_t)(gs2 & 255)*DD*414 + (gs2>>8)*18 + hs2*9 + k82;
    int d1 = u1*16, d2 = u2*16;

    __syncthreads();

    {
        uint4 a0 = ntload4(zlin + cb1);
        *(uint4*)(smb + XB0O + d1) = a0;
        if (l < 8){
            uint4 a1 = ntload4(zlin + cb2);
            *(uint4*)(smb + XB0O + d2) = a1;
        }
    }
    __syncthreads();

    const float* bias0L = (const float*)(smb+B0O);
    const float* bias1L = (const float*)(smb+B1O);

    for (int step = 0; step < DD + DY; ++step){
        const int xb  = (step & 1) ? XB1O : XB0O;
        const int xbn = (step & 1) ? XB0O : XB1O;
        const bool do_stage = (step + 1 < DD);

        {
            uint4 sv0, sv1; sv0.x=sv0.y=sv0.z=sv0.w=0u; sv1 = sv0;
            if (do_stage){
                const uint4* sp = zlin + (size_t)(step+1)*414;
                sv0 = ntload4(sp + cb1);
                if (l < 8) sv1 = ntload4(sp + cb2);
            }
            f32x4 acc[4][2];
            #pragma unroll
            for (int mi=0;mi<4;mi++){
                int j = 16*w + lhi*4 + mi;
                f32x4 a;
                a[0]=bias0L[j]; a[1]=bias0L[128+j]; a[2]=bias0L[256+j]; a[3]=bias0L[384+j];
                acc[mi][0] = a; acc[mi][1] = a;
            }
            #pragma unroll
            for (int kt=0; kt<7; ++kt){
                const v8bf* wrow = w0p + (size_t)(kt*32 + w*4)*64 + l;
                v8bf A0 = wrow[0], A1 = wrow[64], A2 = wrow[128], A3 = wrow[192];
                int k8 = kt*4 + lhi;
                bool inx = (k8 <= 8);
                const char* hib = inx ? (smb + xb + k8*512) : (smb + H0O + (k8-9)*512);
                int losh = inx ? 4608 : 9728;
                v8bf BH0 = *(const v8bf*)(hib + llo*16);
                v8bf BH1 = *(const v8bf*)(hib + 256 + llo*16);
                v8bf BL0 = *(const v8bf*)(hib + losh + llo*16);
                v8bf BL1 = *(const v8bf*)(hib + losh + 256 + llo*16);
                MFMA_(acc[0][0], A0, BH0); MFMA_(acc[0][0], A0, BL0);
                MFMA_(acc[1][0], A1, BH0); MFMA_(acc[1][0], A1, BL0);
                MFMA_(acc[2][0], A2, BH0); MFMA_(acc[2][0], A2, BL0);
                MFMA_(acc[3][0], A3, BH0); MFMA_(acc[3][0], A3, BL0);
                MFMA_(acc[0][1], A0, BH1); MFMA_(acc[0][1], A0, BL1);
                MFMA_(acc[1][1], A1, BH1); MFMA_(acc[1][1], A1, BL1);
                MFMA_(acc[2][1], A2, BH1); MFMA_(acc[2][1], A2, BL1);
                MFMA_(acc[3][1], A3, BH1); MFMA_(acc[3][1], A3, BL1);
            }
            if (do_stage){
                *(uint4*)(smb + xbn + d1) = sv0;
                if (l < 8) *(uint4*)(smb + xbn + d2) = sv1;
            }
            __syncthreads();   // B1

            if (step < DD && t < 288){
                const unsigned short* hp = (const unsigned short*)(smb + xb + t*16);
                const unsigned short* lp = (const unsigned short*)(smb + xb + 4608 + t*16);
                float* xs = (float*)(smb + X2O);
                #pragma unroll
                for (int e=0;e<8;e++) xs[e*288+t] += bf2f(hp[e]) + bf2f(lp[e]);
            }
            const int j8 = 2*w + (lhi>>1);
            const int sub = (lhi&1)*8;
            #pragma unroll
            for (int nt=0;nt<2;nt++){
                unsigned short hh[4], hl[4];
                #pragma unroll
                for (int mi=0;mi<4;mi++){
                    float* cslot = (float*)(smb + C0O) + (mi*2+nt)*512 + t;
                    f32x4 a = acc[mi][nt];
                    float ii = fsig(a[0]), ff = fsig(a[1]), gg = ftanh(a[2]), oo = fsig(a[3]);
                    float c = ff*cslot[0] + ii*gg;
                    cslot[0] = c;
                    float h = oo*ftanh(c);
                    hh[mi] = f2bf(h);
                    hl[mi] = f2bf(h - bf2f(hh[mi]));
                }
                uint2 ph, pl;
                ph.x = (unsigned)hh[0] | ((unsigned)hh[1]<<16);
                ph.y = (unsigned)hh[2] | ((unsigned)hh[3]<<16);
                pl.x = (unsigned)hl[0] | ((unsigned)hl[1]<<16);
                pl.y = (unsigned)hl[2] | ((unsigned)hl[3]<<16);
                int bo = j8*512 + (nt*16+llo)*16 + sub;
                *(uint2*)(smb + H0O + bo)        = ph;
                *(uint2*)(smb + H0O + 9728 + bo) = pl;
                *(uint2*)(smb + U1O + bo)         = ph;
                *(uint2*)(smb + U1O + 16384 + bo) = pl;
            }
            __syncthreads();   // B2
        }

        {
            f32x4 acc1[4][2];
            #pragma unroll
            for (int mi=0;mi<4;mi++){
                int j = 16*w + lhi*4 + mi;
                f32x4 a;
                a[0]=bias1L[j]; a[1]=bias1L[128+j]; a[2]=bias1L[256+j]; a[3]=bias1L[384+j];
                acc1[mi][0] = a; acc1[mi][1] = a;
            }
            #pragma unroll
            for (int kt=0; kt<8; ++kt){
                const v8bf* wrow = w1p + (size_t)(kt*32 + w*4)*64 + l;
                v8bf A0 = wrow[0], A1 = wrow[64], A2 = wrow[128], A3 = wrow[192];
                const char* hib = smb + U1O + (kt*4+lhi)*512;
                v8bf BH0 = *(const v8bf*)(hib + llo*16);
                v8bf BH1 = *(const v8bf*)(hib + 256 + llo*16);
                v8bf BL0 = *(const v8bf*)(hib + 16384 + llo*16);
                v8bf BL1 = *(const v8bf*)(hib + 16384 + 256 + llo*16);
                MFMA_(acc1[0][0], A0, BH0); MFMA_(acc1[0][0], A0, BL0);
                MFMA_(acc1[1][0], A1, BH0); MFMA_(acc1[1][0], A1, BL0);
                MFMA_(acc1[2][0], A2, BH0); MFMA_(acc1[2][0], A2, BL0);
                MFMA_(acc1[3][0], A3, BH0); MFMA_(acc1[3][0], A3, BL0);
                MFMA_(acc1[0][1], A0, BH1); MFMA_(acc1[0][1], A0, BL1);
                MFMA_(acc1[1][1], A1, BH1); MFMA_(acc1[1][1], A1, BL1);
                MFMA_(acc1[2][1], A2, BH1); MFMA_(acc1[2][1], A2, BL1);
                MFMA_(acc1[3][1], A3, BH1); MFMA_(acc1[3][1], A3, BL1);
            }
            __syncthreads();   // B3

            const int j8 = 2*w + (lhi>>1);
            const int sub = (lhi&1)*8;
            #pragma unroll
            for (int nt=0;nt<2;nt++){
                unsigned short hh[4], hl[4];
                #pragma unroll
                for (int mi=0;mi<4;mi++){
                    float* cslot = (float*)(smb + C1O) + (mi*2+nt)*512 + t;
                    f32x4 a = acc1[mi][nt];
                    float ii = fsig(a[0]), ff = fsig(a[1]), gg = ftanh(a[2]), oo = fsig(a[3]);
                    float c = ff*cslot[0] + ii*gg;
                    cslot[0] = c;
                    float h = oo*ftanh(c);
                    hh[mi] = f2bf(h);
                    hl[mi] = f2bf(h - bf2f(hh[mi]));
                }
                uint2 ph, pl;
                ph.x = (unsigned)hh[0] | ((unsigned)hh[1]<<16);
                ph.y = (unsigned)hh[2] | ((unsigned)hh[3]<<16);
                pl.x = (unsigned)hl[0] | ((unsigned)hl[1]<<16);
                pl.y = (unsigned)hl[2] | ((unsigned)hl[3]<<16);
                int bo = (16+j8)*512 + (nt*16+llo)*16 + sub;
                *(uint2*)(smb + U1O + bo)         = ph;
                *(uint2*)(smb + U1O + 16384 + bo) = pl;
            }
        }

        if (step == DD-1){
            __syncthreads();
            if (t < 288){
                const float* xs = (const float*)(smb + X2O);
                __align__(16) unsigned short hb8[8], lb8[8];
                #pragma unroll
                for (int e=0;e<8;e++){
                    float v = xs[e*288+t] * (1.f/(float)DD);
                    unsigned short h = f2bf(v);
                    hb8[e] = h;
                    lb8[e] = f2bf(v - bf2f(h));
                }
                *(uint4*)(smb + XB0O + t*16)        = *(const uint4*)hb8;
                *(uint4*)(smb + XB0O + 4608 + t*16) = *(const uint4*)lb8;
                *(uint4*)(smb + XB1O + t*16)        = *(const uint4*)hb8;
                *(uint4*)(smb + XB1O + 4608 + t*16) = *(const uint4*)lb8;
            }
        }

        if (step >= DD){
            __syncthreads();
            if (t < 256){
                int seq = t>>3, l8 = t&7;
                const unsigned short* uh = (const unsigned short*)(smb+U1O);
                const unsigned short* ul = (const unsigned short*)(smb+U1O+16384);
                const float* fw = (const float*)(smb+FCO);
                float a = 0.f;
                #pragma unroll
                for (int half=0; half<2; ++half){
                    int k8 = 16 + l8*2 + half;
                    int base = (k8*32 + seq)*8;
                    #pragma unroll
                    for (int e=0;e<8;e++){
                        int j = l8*16 + half*8 + e;
                        a = fmaf(fw[j], bf2f(uh[base+e]) + bf2f(ul[base+e]), a);
                    }
                }
                a += __shfl_down(a, 4, 8);
                a += __shfl_down(a, 2, 8);
                a += __shfl_down(a, 1, 8);
                if (l8 == 0){
                    int gseq = blk*32 + seq, n = gseq>>8, bb = gseq&255;
                    float yv = fmaxf(a + ((const float*)(smb+INO))[seq] + fw[128], 0.f);
                    __builtin_nontemporal_store(yv, &outy[((size_t)bb*DY + (step-DD))*DN + n]);
                }
            }
        }
    }
}

// ---------------------------------------------------------------------------
extern "C" void kernel_launch(void* const* d_in, const int* in_sizes, int n_in,
                              void* d_out, int out_size, void* d_ws, size_t ws_size,
                              hipStream_t stream)
{
    const float* x         = (const float*)d_in[0];
    const float* adj_real  = (const float*)d_in[1];
    const float* infection = (const float*)d_in[2];
    const int*   day_order = (const int*)  d_in[3];
    const float* gl_w1     = (const float*)d_in[4];
    const float* gl_b1     = (const float*)d_in[5];
    const float* gl_w2     = (const float*)d_in[6];
    const float* gl_b2     = (const float*)d_in[7];
    const float* glp       = (const float*)d_in[8];
    const float* gcn_w     = (const float*)d_in[9];
    const float* vvec      = (const float*)d_in[10];
    const float* wih0      = (const float*)d_in[11];
    const float* whh0      = (const float*)d_in[12];
    const float* b0        = (const float*)d_in[13];
    const float* wih1      = (const float*)d_in[14];
    const float* whh1      = (const float*)d_in[15];
    const float* b1        = (const float*)d_in[16];
    const float* fcw       = (const float*)d_in[17];
    const float* fcb       = (const float*)d_in[18];

    uint8_t* wsb = (uint8_t*)d_ws;
    uint4*          zlin = (uint4*)(wsb);
    unsigned short* wb0  = (unsigned short*)(wsb + WB0_OFF);
    unsigned short* wb1  = (unsigned short*)(wsb + WB1_OFF);
    unsigned short* wpk  = (unsigned short*)(wsb + WPK_OFF);
    unsigned short* gpk  = (unsigned short*)(wsb + GPK_OFF);
    float* out_adj = (float*)d_out;
    float* out_y   = out_adj + ADJSZ;

    kernPrep<<<dim3(1248), dim3(256), 0, stream>>>(wih0, whh0, wih1, whh1,
                                                   gl_w1, gl_w2, gcn_w,
                                                   wb0, wb1, wpk, gpk);
    kernA<<<dim3(DB*DD), dim3(256), 0, stream>>>(x, adj_real, infection, day_order,
                                                 gl_b1, gl_b2, glp, vvec,
                                                 (const v8bf*)wpk, (const v8bf*)gpk,
                                                 out_adj, zlin);
    kernB<<<dim3(GBLK), dim3(512), 0, stream>>>(zlin, (const v8bf*)wb0,
                                                (const v8bf*)wb1, b0, b1, infection,
                                                fcw, fcb, out_y);
}